// Round 10
// baseline (182.780 us; speedup 1.0000x reference)
//
#include <hip/hip_runtime.h>
#include <cmath>

// CrossAttention: B=4, N=4096, M=1024, QD=320, CD=768, ID=512, H=8, Dh=64
// fp32 I/O; bf16 MFMA internals, fp32 accumulate.
// r10: flash = 2-wave blocks (128 thr), 64 q/wave, split-half key processing
// (halved s-liveness + sPT); gemm_kv 128x128 tiles.
constexpr int BATCH  = 4;
constexpr int SEQ_N  = 4096;
constexpr int SEQ_M  = 1024;
constexpr int QD     = 320;
constexpr int CD     = 768;
constexpr int ID     = 512;
constexpr float QFOLD = 0.125f * 1.44269504f;   // SCALE*log2e folded into Wq
constexpr float EK2F  = -8.0f * 1.44269504f;    // fixed softmax shift (log2 dom)

typedef __bf16 bf16x8 __attribute__((ext_vector_type(8)));
typedef __bf16 bf16x4 __attribute__((ext_vector_type(4)));
typedef __bf16 bf16x2 __attribute__((ext_vector_type(2)));
typedef float  f32x4  __attribute__((ext_vector_type(4)));

__device__ __forceinline__ void gload_lds16(const __bf16* g, __bf16* l) {
    __builtin_amdgcn_global_load_lds(
        (const __attribute__((address_space(1))) void*)g,
        (__attribute__((address_space(3))) void*)l, 16, 0, 0);
}

// ---------------------------------------------------------------------------
// One dispatch: fp32->bf16 for x/ctx (blocks 0..4095) + weight transpose/cvt
// (blocks 4096..5183).  Wq pre-scaled by QFOLD.
// ---------------------------------------------------------------------------
__global__ __launch_bounds__(256)
void cvt_all(const float* __restrict__ x, const float* __restrict__ ctx,
             const float* __restrict__ Wq, const float* __restrict__ Wk,
             const float* __restrict__ Wv, const float* __restrict__ Wo,
             __bf16* __restrict__ xb, __bf16* __restrict__ ctxb,
             __bf16* __restrict__ WqT, __bf16* __restrict__ WkT,
             __bf16* __restrict__ WvT, __bf16* __restrict__ WoT) {
    __shared__ float tile[32][33];
    int bid = blockIdx.x;
    if (bid < 4096) {
        constexpr int NX8 = SEQ_N * BATCH * QD / 8;   // 655360
        int i = bid * 256 + threadIdx.x;
        const float* s; __bf16* d; int j;
        if (i < NX8) { s = x; d = xb; j = i; }
        else         { s = ctx; d = ctxb; j = i - NX8; }
        const float4* sp = reinterpret_cast<const float4*>(s) + (size_t)j * 2;
        float4 a = sp[0], b = sp[1];
        bf16x8 o = { (__bf16)a.x, (__bf16)a.y, (__bf16)a.z, (__bf16)a.w,
                     (__bf16)b.x, (__bf16)b.y, (__bf16)b.z, (__bf16)b.w };
        reinterpret_cast<bf16x8*>(d)[j] = o;
        return;
    }
    int wb = bid - 4096;
    const float* W; __bf16* WT; int K, N, tid; float scl = 1.0f;
    if (wb < 160)      { W = Wq; WT = WqT; K = 320; N = 512; tid = wb; scl = QFOLD; }
    else if (wb < 544) { W = Wk; WT = WkT; K = 768; N = 512; tid = wb - 160; }
    else if (wb < 928) { W = Wv; WT = WvT; K = 768; N = 512; tid = wb - 544; }
    else               { W = Wo; WT = WoT; K = 512; N = 320; tid = wb - 928; }
    int kt = K / 32;
    int k0 = (tid % kt) * 32, n0 = (tid / kt) * 32;
    int tc = threadIdx.x & 31, tr = threadIdx.x >> 5;
#pragma unroll
    for (int p = 0; p < 4; ++p)
        tile[p * 8 + tr][tc] = W[(size_t)(k0 + p * 8 + tr) * N + n0 + tc];
    __syncthreads();
#pragma unroll
    for (int p = 0; p < 4; ++p)
        WT[(size_t)(n0 + p * 8 + tr) * K + k0 + tc] = (__bf16)(tile[tc][p * 8 + tr] * scl);
}

// ---------------------------------------------------------------------------
// KV projection: C = ctxb @ [WkT|WvT]^T.  128x128 tiles (grid 256), 4 waves
// (2x2 of 64x64), BK=64 dbuf (64 KB), XOR chunk swizzle, operand-swapped MFMA
// (32 MFMA/wave/iter).  blockIdx.y<4 -> Kb row-major; >=4 -> Vt (b,h,d,m) via
// per-wave LDS transpose + 128B-contiguous stores.
// ---------------------------------------------------------------------------
__global__ __launch_bounds__(256)
void gemm_kv(const __bf16* __restrict__ A, const __bf16* __restrict__ BT,
             __bf16* __restrict__ Kb, __bf16* __restrict__ Vt, int M, int K) {
    __shared__ __attribute__((aligned(16))) __bf16 sA[2][128][64];
    __shared__ __attribute__((aligned(16))) __bf16 sB[2][128][64];

    const int t = threadIdx.x;
    const int wave = t >> 6, lane = t & 63;
    const int q = lane >> 4, c = lane & 15;
    const int wm = wave >> 1, wn = wave & 1;
    const int row0 = blockIdx.x * 128, col0 = blockIdx.y * 128;
    const int srow = lane >> 3, sch = lane & 7;
    const int fch = sch ^ srow;

    auto stage = [&](int buf, int k0) {
#pragma unroll
        for (int i = 0; i < 4; ++i) {
            int r = wave * 32 + i * 8;
            gload_lds16(A + (size_t)(row0 + r + srow) * K + k0 + fch * 8,
                        &sA[buf][r][0] + lane * 8);
            gload_lds16(BT + (size_t)(col0 + r + srow) * K + k0 + fch * 8,
                        &sB[buf][r][0] + lane * 8);
        }
    };

    f32x4 acc[4][4] = {};   // D[n=j*16+q*4+r][m=i*16+c] (operand-swapped)
    stage(0, 0);
    const int iters = K >> 6;
    for (int it = 0; it < iters; ++it) {
        const int p = it & 1;
        __syncthreads();
        if (it + 1 < iters) stage(p ^ 1, (it + 1) * 64);
#pragma unroll
        for (int ks = 0; ks < 2; ++ks) {
            const int so = ((ks * 4 + q) ^ (c & 7)) * 8;
            bf16x8 am[4], bn[4];
#pragma unroll
            for (int i = 0; i < 4; ++i)
                am[i] = *reinterpret_cast<const bf16x8*>(&sA[p][wm * 64 + i * 16 + c][0] + so);
#pragma unroll
            for (int j = 0; j < 4; ++j)
                bn[j] = *reinterpret_cast<const bf16x8*>(&sB[p][wn * 64 + j * 16 + c][0] + so);
#pragma unroll
            for (int i = 0; i < 4; ++i)
#pragma unroll
                for (int j = 0; j < 4; ++j)
                    acc[i][j] = __builtin_amdgcn_mfma_f32_16x16x32_bf16(bn[j], am[i], acc[i][j], 0, 0, 0);
        }
    }

    if (blockIdx.y < 4) {
        // K half: packed bf16x4 stores (lane holds row m, 4 consecutive cols)
#pragma unroll
        for (int i = 0; i < 4; ++i)
#pragma unroll
            for (int j = 0; j < 4; ++j) {
                int mrow = row0 + wm * 64 + i * 16 + c;
                int ncol = col0 + wn * 64 + j * 16 + q * 4;
                bf16x4 v = { (__bf16)acc[i][j][0], (__bf16)acc[i][j][1],
                             (__bf16)acc[i][j][2], (__bf16)acc[i][j][3] };
                *reinterpret_cast<bf16x4*>(&Kb[(size_t)mrow * 512 + ncol]) = v;
            }
    } else {
        // V half: per-wave 64x64 transpose through LDS, coalesced Vt stores
        __syncthreads();   // all LDS reads done; reuse sA/sB region
        __bf16* ldsT = ((__bf16*)sA) + wave * 4608;   // [64][72]
#pragma unroll
        for (int i = 0; i < 4; ++i)
#pragma unroll
            for (int j = 0; j < 4; ++j)
#pragma unroll
                for (int r = 0; r < 4; ++r)
                    ldsT[(j * 16 + q * 4 + r) * 72 + i * 16 + c] = (__bf16)acc[i][j][r];
        int b = row0 >> 10;
        int mcol = (row0 & 1023) + wm * 64;
        int dbase = col0 - 512 + wn * 64;
#pragma unroll
        for (int it = 0; it < 8; ++it) {
            int dloc = it * 8 + (lane >> 3);
            int ch = lane & 7;
            int dg = dbase + dloc;
            int h = dg >> 6, d = dg & 63;
            *reinterpret_cast<bf16x8*>(
                Vt + (((size_t)((b * 8 + h) * 64 + d)) << 10) + mcol + ch * 8) =
                *reinterpret_cast<const bf16x8*>(&ldsT[dloc * 72 + ch * 8]);
        }
    }
}

// ---------------------------------------------------------------------------
// Flash attention v5: 128-thread (2-wave) blocks, 64 queries/wave (qt=4),
// fused Q-projection prologue.  Main loop: 64-key tiles, single-buffered
// sK/sV, SPLIT-HALF processing (keys 0..31 then 32..63): QK-half -> exp ->
// PV-half, halving s-liveness (32 VGPRs) and sPT ([64][40]/wave, 2-way-free).
// Softmax: exp2(s) with EK2F in MFMA C-init; l via ones-MFMA.
// LDS: sK 8K + sV 8K + sPT 10.25K = 26.6 KB -> 6 blocks/CU cap, grid 1024.
// ---------------------------------------------------------------------------
__global__ __launch_bounds__(128, 2)
void flash_attn(const __bf16* __restrict__ xb, const __bf16* __restrict__ WqT,
                const __bf16* __restrict__ Kb, const __bf16* __restrict__ Vt,
                __bf16* __restrict__ AO) {
    __shared__ __attribute__((aligned(16))) __bf16 smem[13312];
    __bf16* sK  = smem;            // [64][64]
    __bf16* sV  = smem + 4096;     // [64][64]
    __bf16* sPT = smem + 8192;     // 2 waves x [64][40]
    // prologue overlays: sX = smem [128][64]; sW = smem+8192 [64][64]

    const int t = threadIdx.x;
    const int wave = t >> 6, lane = t & 63;
    const int q = lane >> 4, c = lane & 15;
    const int bh = blockIdx.y;
    const int b = bh >> 3, h = bh & 7;
    const int n0 = blockIdx.x * 128;
    const int srow = lane >> 3, sch = lane & 7;
    const int fch = sch ^ srow;

    __bf16* sQw = sPT + wave * 2560;   // per-wave [64][40]

    // ---- Prologue: Q^T[64 d][128 q] = WqT_h @ xb^T (K=320, 5 iters) ------
    f32x4 accQ[4][4] = {};   // [dt][qt], C-layout: row d=dt*16+q*4+r, col q=c
    {
        __bf16* sX = smem;
        __bf16* sW = smem + 8192;
        for (int k0 = 0; k0 < QD; k0 += 64) {
            __syncthreads();
#pragma unroll
            for (int i = 0; i < 8; ++i) {
                int r = wave * 64 + i * 8;
                gload_lds16(xb + (size_t)(b * SEQ_N + n0 + r + srow) * QD + k0 + fch * 8,
                            sX + r * 64 + lane * 8);
            }
#pragma unroll
            for (int i = 0; i < 4; ++i) {
                int r = wave * 32 + i * 8;
                gload_lds16(WqT + (size_t)(h * 64 + r + srow) * QD + k0 + fch * 8,
                            sW + r * 64 + lane * 8);
            }
            __syncthreads();
#pragma unroll
            for (int ks = 0; ks < 2; ++ks) {
                const int so = ((ks * 4 + q) ^ (c & 7)) * 8;
                bf16x8 aw[4], bx[4];
#pragma unroll
                for (int dt = 0; dt < 4; ++dt)
                    aw[dt] = *reinterpret_cast<const bf16x8*>(sW + (dt * 16 + c) * 64 + so);
#pragma unroll
                for (int qt = 0; qt < 4; ++qt)
                    bx[qt] = *reinterpret_cast<const bf16x8*>(sX + (wave * 64 + qt * 16 + c) * 64 + so);
#pragma unroll
                for (int dt = 0; dt < 4; ++dt)
#pragma unroll
                    for (int qt = 0; qt < 4; ++qt)
                        accQ[dt][qt] = __builtin_amdgcn_mfma_f32_16x16x32_bf16(aw[dt], bx[qt], accQ[dt][qt], 0, 0, 0);
            }
        }
    }
    __syncthreads();   // both waves done reading sW/sX before region reuse

    // C->B layout per d-half through per-wave sPT slice
    bf16x8 aq[4][2];
#pragma unroll
    for (int ks = 0; ks < 2; ++ks) {
#pragma unroll
        for (int cti = 0; cti < 2; ++cti) {
            int dt = ks * 2 + cti;
#pragma unroll
            for (int qt = 0; qt < 4; ++qt) {
                bf16x2 w0 = { (__bf16)accQ[dt][qt][0], (__bf16)accQ[dt][qt][1] };
                bf16x2 w1 = { (__bf16)accQ[dt][qt][2], (__bf16)accQ[dt][qt][3] };
                __bf16* pr = sQw + (qt * 16 + c) * 40 + cti * 16 + q * 4;
                *reinterpret_cast<bf16x2*>(pr)     = w0;
                *reinterpret_cast<bf16x2*>(pr + 2) = w1;
            }
        }
#pragma unroll
        for (int qt = 0; qt < 4; ++qt)
            aq[qt][ks] = *reinterpret_cast<const bf16x8*>(sQw + (qt * 16 + c) * 40 + q * 8);
    }

    // ---- Main loop -------------------------------------------------------
    auto stageKV = [&](int m0) {
#pragma unroll
        for (int i = 0; i < 4; ++i) {
            int r = wave * 32 + i * 8;
            gload_lds16(Kb + (size_t)(b * SEQ_M + m0 + r + srow) * ID + h * 64 + fch * 8,
                        sK + r * 64 + lane * 8);
            gload_lds16(Vt + (((size_t)((b * 8 + h) * 64 + r + srow)) << 10) + m0 + fch * 8,
                        sV + r * 64 + lane * 8);
        }
    };

    const bf16x8 ONES = { (__bf16)1.0f, (__bf16)1.0f, (__bf16)1.0f, (__bf16)1.0f,
                          (__bf16)1.0f, (__bf16)1.0f, (__bf16)1.0f, (__bf16)1.0f };
    f32x4 accO[4][4] = {};   // [qt][nt]
    f32x4 accL[4] = {};      // [qt]

    for (int m0 = 0; m0 < SEQ_M; m0 += 64) {
        __syncthreads();               // prior tile reads done (2-wave sync)
        stageKV(m0);
        __syncthreads();               // staged

#pragma unroll
        for (int hh = 0; hh < 2; ++hh) {    // key halves: hh*32 .. hh*32+31
            // S^T half = K_half * Q^T + EK2F
            f32x4 s[4][2];
#pragma unroll
            for (int qt = 0; qt < 4; ++qt)
#pragma unroll
                for (int cti = 0; cti < 2; ++cti)
                    s[qt][cti] = f32x4{ EK2F, EK2F, EK2F, EK2F };
#pragma unroll
            for (int ks = 0; ks < 2; ++ks) {
                const int so = ((ks * 4 + q) ^ (c & 7)) * 8;
#pragma unroll
                for (int cti = 0; cti < 2; ++cti) {
                    bf16x8 ak = *reinterpret_cast<const bf16x8*>(
                        sK + ((hh * 2 + cti) * 16 + c) * 64 + so);
#pragma unroll
                    for (int qt = 0; qt < 4; ++qt)
                        s[qt][cti] = __builtin_amdgcn_mfma_f32_16x16x32_bf16(ak, aq[qt][ks], s[qt][cti], 0, 0, 0);
                }
            }
            // p = exp2(s); write local-key cols to per-wave sPT half
#pragma unroll
            for (int qt = 0; qt < 4; ++qt)
#pragma unroll
                for (int cti = 0; cti < 2; ++cti) {
                    float p0 = exp2f(s[qt][cti][0]);
                    float p1 = exp2f(s[qt][cti][1]);
                    float p2 = exp2f(s[qt][cti][2]);
                    float p3 = exp2f(s[qt][cti][3]);
                    bf16x2 w0 = { (__bf16)p0, (__bf16)p1 };
                    bf16x2 w1 = { (__bf16)p2, (__bf16)p3 };
                    __bf16* pr = sQw + (qt * 16 + c) * 40 + cti * 16 + q * 4;
                    *reinterpret_cast<bf16x2*>(pr)     = w0;
                    *reinterpret_cast<bf16x2*>(pr + 2) = w1;
                }
            // O^T += V^T_half * P^T_half ; l += ones * P^T_half
            const int soh = ((hh * 4 + q) ^ (c & 7)) * 8;
            bf16x8 bp[4];
#pragma unroll
            for (int qt = 0; qt < 4; ++qt)
                bp[qt] = *reinterpret_cast<const bf16x8*>(sQw + (qt * 16 + c) * 40 + q * 8);
#pragma unroll
            for (int qt = 0; qt < 4; ++qt)
                accL[qt] = __builtin_amdgcn_mfma_f32_16x16x32_bf16(ONES, bp[qt], accL[qt], 0, 0, 0);
#pragma unroll
            for (int nt = 0; nt < 4; ++nt) {
                bf16x8 av = *reinterpret_cast<const bf16x8*>(sV + (nt * 16 + c) * 64 + soh);
#pragma unroll
                for (int qt = 0; qt < 4; ++qt)
                    accO[qt][nt] = __builtin_amdgcn_mfma_f32_16x16x32_bf16(av, bp[qt], accO[qt][nt], 0, 0, 0);
            }
        }
    }

    // epilogue: O /= l, packed 8B stores
#pragma unroll
    for (int qt = 0; qt < 4; ++qt) {
        float inv = 1.0f / accL[qt][0];
        size_t rowb = (size_t)(b * SEQ_N + n0 + wave * 64 + qt * 16 + c) * ID + h * 64;
#pragma unroll
        for (int nt = 0; nt < 4; ++nt) {
            bf16x4 v = { (__bf16)(accO[qt][nt][0] * inv), (__bf16)(accO[qt][nt][1] * inv),
                         (__bf16)(accO[qt][nt][2] * inv), (__bf16)(accO[qt][nt][3] * inv) };
            *reinterpret_cast<bf16x4*>(&AO[rowb + nt * 16 + q * 4]) = v;
        }
    }
}

// ---------------------------------------------------------------------------
// Output projection: out[16384 x 320] = AO @ WoT^T + bias, fp32 out.
// 128x64 tiles (grid 640), wave 64x32, BK=64 dbuf, XOR swizzle,
// operand-swapped -> float4 stores.  (r9-verified)
// ---------------------------------------------------------------------------
__global__ __launch_bounds__(256)
void gemm_out(const __bf16* __restrict__ A, const __bf16* __restrict__ BT,
              const float* __restrict__ bias, float* __restrict__ C,
              int M, int N, int K) {
    __shared__ __attribute__((aligned(16))) __bf16 sA[2][128][64];
    __shared__ __attribute__((aligned(16))) __bf16 sB[2][64][64];

    const int t = threadIdx.x;
    const int wave = t >> 6, lane = t & 63;
    const int q = lane >> 4, c = lane & 15;
    const int wm = wave >> 1, wn = wave & 1;
    const int row0 = blockIdx.x * 128, col0 = blockIdx.y * 64;
    const int srow = lane >> 3, sch = lane & 7;
    const int fch = sch ^ srow;

    auto stage = [&](int buf, int k0) {
#pragma unroll
        for (int i = 0; i < 4; ++i) {
            int r = wave * 32 + i * 8;
            gload_lds16(A + (size_t)(row0 + r + srow) * K + k0 + fch * 8,
                        &sA[buf][r][0] + lane * 8);
        }
#pragma unroll
        for (int i = 0; i < 2; ++i) {
            int r = wave * 16 + i * 8;
            gload_lds16(BT + (size_t)(col0 + r + srow) * K + k0 + fch * 8,
                        &sB[buf][r][0] + lane * 8);
        }
    };

    f32x4 acc[4][2] = {};
    stage(0, 0);
    const int iters = K >> 6;
    for (int it = 0; it < iters; ++it) {
        const int p = it & 1;
        __syncthreads();
        if (it + 1 < iters) stage(p ^ 1, (it + 1) * 64);
#pragma unroll
        for (int ks = 0; ks < 2; ++ks) {
            const int so = ((ks * 4 + q) ^ (c & 7)) * 8;
            bf16x8 am[4], bn[2];
#pragma unroll
            for (int i = 0; i < 4; ++i)
                am[i] = *reinterpret_cast<const bf16x8*>(&sA[p][wm * 64 + i * 16 + c][0] + so);
#pragma unroll
            for (int j = 0; j < 2; ++j)
                bn[j] = *reinterpret_cast<const bf16x8*>(&sB[p][wn * 32 + j * 16 + c][0] + so);
#pragma unroll
            for (int i = 0; i < 4; ++i)
#pragma unroll
                for (int j = 0; j < 2; ++j)
                    acc[i][j] = __builtin_amdgcn_mfma_f32_16x16x32_bf16(bn[j], am[i], acc[i][j], 0, 0, 0);
        }
    }

#pragma unroll
    for (int i = 0; i < 4; ++i)
#pragma unroll
        for (int j = 0; j < 2; ++j) {
            int mrow = row0 + wm * 64 + i * 16 + c;
            int ncol = col0 + wn * 32 + j * 16 + q * 4;
            float4 v = { acc[i][j][0] + bias[ncol + 0],
                         acc[i][j][1] + bias[ncol + 1],
                         acc[i][j][2] + bias[ncol + 2],
                         acc[i][j][3] + bias[ncol + 3] };
            *reinterpret_cast<float4*>(&C[(size_t)mrow * N + ncol]) = v;
        }
}

// ---------------------------------------------------------------------------
extern "C" void kernel_launch(void* const* d_in, const int* in_sizes, int n_in,
                              void* d_out, int out_size, void* d_ws, size_t ws_size,
                              hipStream_t stream) {
    const float* x   = (const float*)d_in[0];
    const float* ctx = (const float*)d_in[1];
    const float* Wq  = (const float*)d_in[2];
    const float* Wk  = (const float*)d_in[3];
    const float* Wv  = (const float*)d_in[4];
    const float* Wo  = (const float*)d_in[5];
    const float* bo  = (const float*)d_in[6];
    float* out = (float*)d_out;

    char* ws = (char*)d_ws;
    __bf16* xb   = (__bf16*)(ws + 0);                 // 16384x320 (stays live)
    __bf16* ctxb = (__bf16*)(ws + 10485760);          // 4096x768
    __bf16* AO   = (__bf16*)(ws + 16777216);          // 16384x512
    __bf16* Kb   = (__bf16*)(ws + 33554432);          // 4096x512
    __bf16* Vt   = (__bf16*)(ws + 37748736);          // (32,64,1024)
    __bf16* WqT  = (__bf16*)(ws + 41943040);          // 512x320 (pre-scaled)
    __bf16* WkT  = (__bf16*)(ws + 42270720);          // 512x768 \ adjacent
    __bf16* WvT  = (__bf16*)(ws + 43057152);          // 512x768 / = 1024x768
    __bf16* WoT  = (__bf16*)(ws + 43843584);          // 320x512

    const int MX = BATCH * SEQ_N;   // 16384
    const int MC = BATCH * SEQ_M;   // 4096

    cvt_all<<<dim3(5184), dim3(256), 0, stream>>>(x, ctx, Wq, Wk, Wv, Wo,
                                                  xb, ctxb, WqT, WkT, WvT, WoT);

    // fused K+V projection, 128x128 tiles (y<4 -> Kb, y>=4 -> Vt transposed)
    gemm_kv<<<dim3(MC / 128, 8), dim3(256), 0, stream>>>(ctxb, WkT, Kb, Vt, MC, CD);

    // flash with fused Q-projection (128 queries / 2-wave block)
    flash_attn<<<dim3(SEQ_N / 128, 32), dim3(128), 0, stream>>>(xb, WqT, Kb, Vt, AO);

    // output projection + bias (fp32 out)
    gemm_out<<<dim3(MX / 128, QD / 64), dim3(256), 0, stream>>>(AO, WoT, bo, out, MX, QD, ID);
}